// Round 5
// baseline (46.991 us; speedup 1.0000x reference)
//
#include <hip/hip_runtime.h>
#include <hip/hip_bf16.h>

static constexpr int H = 512;
static constexpr int W = 512;
static constexpr int NIMG = 8;

// ws layout (bytes from d_ws):
//   F       @ 0        : [16][H][W] u16 = 8 MiB (axis-0 distance; 0xFFFF = empty column)
//   maxsq   @ 8Mi      : 16 f32  (task = dir*8+img; dir0 = max_{a} D_b^2, dir1 = max_{b} D_a^2)
//   anyflag @ 8Mi+64   : 16 int  (t<8: any(a_t), t>=8: any(b_{t-8}))
//   done    @ 8Mi+128  : 1 int   (completion counter for fused finalize)
//   bm      @ 8Mi+256  : [16][16][512] u32 = 512 KiB (bit r of bm[m][s][c] = mask m pixel (s*32+r, c))

__device__ __forceinline__ int edt_d(unsigned int m, int r, int row0, int ig,
                                     int carry_dn, int carry_up) {
    unsigned int below = m & (0xFFFFFFFFu >> (31 - r));   // bits 0..r
    int pos_dn = below ? (row0 + (31 - __clz((int)below))) : carry_dn;
    unsigned int above = m & (0xFFFFFFFFu << r);          // bits r..31
    int pos_up = above ? (row0 + (__ffs((int)above) - 1)) : carry_up;
    return min(ig - pos_dn, pos_up - ig);
}

__global__ __launch_bounds__(128)
void k_col_edt(const float* __restrict__ A, const float* __restrict__ B,
               unsigned short* __restrict__ F, unsigned int* __restrict__ bm,
               float* __restrict__ maxsq, int* __restrict__ anyflag,
               int* __restrict__ done) {
    const int tid  = threadIdx.x;
    const int quad = tid & 7;          // 4-column group within 32-col tile
    const int seg  = tid >> 3;         // 0..15 (32-row segment)
    const int cg   = blockIdx.x;       // 0..15
    const int m16  = blockIdx.y;       // 0..15

    // fold k_init: only this block touches the slots during this kernel;
    // k_row_env (stream-ordered after) is the only consumer.
    if (cg == 0 && m16 == 0) {
        if (tid < 16) { maxsq[tid] = 0.0f; anyflag[tid] = 0; }
        if (tid == 16) { *done = 0; }
    }

    const int colbase = cg * 32 + quad * 4;
    const float* src = (m16 < NIMG) ? (A + (size_t)m16 * H * W)
                                    : (B + (size_t)(m16 - NIMG) * H * W);
    unsigned short* f = F + (size_t)m16 * H * W;
    const int row0 = seg * 32;

    // 32 independent float4 loads -> 4 column bitmasks
    unsigned int m0 = 0, m1 = 0, m2 = 0, m3 = 0;
    #pragma unroll
    for (int r = 0; r < 32; ++r) {
        float4 v = *reinterpret_cast<const float4*>(src + (size_t)(row0 + r) * W + colbase);
        m0 |= (v.x > 0.5f ? 1u : 0u) << r;
        m1 |= (v.y > 0.5f ? 1u : 0u) << r;
        m2 |= (v.z > 0.5f ? 1u : 0u) << r;
        m3 |= (v.w > 0.5f ? 1u : 0u) << r;
    }

    // persist bitmasks for k_row_env's membership test (replaces float mask re-read)
    {
        uint4 o = make_uint4(m0, m1, m2, m3);
        *reinterpret_cast<uint4*>(&bm[((size_t)m16 * 16 + seg) * W + colbase]) = o;
    }

    const int NEGS = -(1 << 21), POSS = (1 << 21);
    __shared__ int s_hi[16][32];
    __shared__ int s_lo[16][32];
    int4 hi, lo;
    hi.x = m0 ? (row0 + 31 - __clz((int)m0)) : NEGS;
    hi.y = m1 ? (row0 + 31 - __clz((int)m1)) : NEGS;
    hi.z = m2 ? (row0 + 31 - __clz((int)m2)) : NEGS;
    hi.w = m3 ? (row0 + 31 - __clz((int)m3)) : NEGS;
    lo.x = m0 ? (row0 + __ffs((int)m0) - 1) : POSS;
    lo.y = m1 ? (row0 + __ffs((int)m1) - 1) : POSS;
    lo.z = m2 ? (row0 + __ffs((int)m2) - 1) : POSS;
    lo.w = m3 ? (row0 + __ffs((int)m3) - 1) : POSS;
    *reinterpret_cast<int4*>(&s_hi[seg][quad * 4]) = hi;
    *reinterpret_cast<int4*>(&s_lo[seg][quad * 4]) = lo;
    __syncthreads();

    // cross-segment carries (vectorized over the 4 owned columns)
    int4 cdn = {NEGS, NEGS, NEGS, NEGS};
    for (int t = 0; t < seg; ++t) {
        int4 h = *reinterpret_cast<int4*>(&s_hi[t][quad * 4]);
        cdn.x = max(cdn.x, h.x); cdn.y = max(cdn.y, h.y);
        cdn.z = max(cdn.z, h.z); cdn.w = max(cdn.w, h.w);
    }
    int4 cup = {POSS, POSS, POSS, POSS};
    for (int t = seg + 1; t < 16; ++t) {
        int4 l = *reinterpret_cast<int4*>(&s_lo[t][quad * 4]);
        cup.x = min(cup.x, l.x); cup.y = min(cup.y, l.y);
        cup.z = min(cup.z, l.z); cup.w = min(cup.w, l.w);
    }

    // per-row exact axis-0 distance, packed ushort4 stores
    #pragma unroll
    for (int r = 0; r < 32; ++r) {
        const int ig = row0 + r;
        ushort4 o;
        o.x = (unsigned short)min(edt_d(m0, r, row0, ig, cdn.x, cup.x), 65535);
        o.y = (unsigned short)min(edt_d(m1, r, row0, ig, cdn.y, cup.y), 65535);
        o.z = (unsigned short)min(edt_d(m2, r, row0, ig, cdn.z, cup.z), 65535);
        o.w = (unsigned short)min(edt_d(m3, r, row0, ig, cdn.w, cup.w), 65535);
        *reinterpret_cast<ushort4*>(f + (size_t)ig * W + colbase) = o;
    }
}

__global__ __launch_bounds__(512)
void k_row_env(const unsigned short* __restrict__ F, const unsigned int* __restrict__ bm,
               float* __restrict__ maxsq, int* __restrict__ anyflag,
               int* __restrict__ done, float* __restrict__ out) {
    const int task = blockIdx.y;            // 0..15
    const int img  = task & 7;
    const int dir  = task >> 3;             // 0: D_b at a-pixels ; 1: D_a at b-pixels
    const int wave = threadIdx.x >> 6;      // 0..7 -> row within block
    const int lane = threadIdx.x & 63;
    const int row  = blockIdx.x * 8 + wave;
    const int fsel = (dir == 0) ? (NIMG + img) : img;   // EDT source (the other mask)
    const int msel = (dir == 0) ? img : (NIMG + img);   // membership mask
    const unsigned short* frow = F + (size_t)fsel * H * W + (size_t)row * W;
    const int p0 = lane * 8;

    __shared__ float sf[8][528];            // [wave][8 pad | 512 | 8 pad]
    __shared__ float s_wmax[8];
    __shared__ int   s_wany[8];

    // independent 16B loads: f (8x u16) + membership bits (8x u32, L2-resident bm)
    uint4 fu = *reinterpret_cast<const uint4*>(frow + p0);
    const unsigned int* brow = bm + ((size_t)msel * 16 + (row >> 5)) * W + p0;
    uint4 b0 = *reinterpret_cast<const uint4*>(brow);
    uint4 b1 = *reinterpret_cast<const uint4*>(brow + 4);
    const int bit = row & 31;

    float w[24];
    {
        unsigned int uu[4] = {fu.x, fu.y, fu.z, fu.w};
        #pragma unroll
        for (int e = 0; e < 4; ++e) {
            int dl = (int)(uu[e] & 0xFFFFu);
            int dh = (int)(uu[e] >> 16);
            w[8 + 2 * e]     = (dl == 65535) ? 1.0e12f : (float)(dl * dl);
            w[8 + 2 * e + 1] = (dh == 65535) ? 1.0e12f : (float)(dh * dh);
        }
    }

    float* srow = &sf[wave][0];
    *reinterpret_cast<float4*>(srow + 8 + p0)     = make_float4(w[8],  w[9],  w[10], w[11]);
    *reinterpret_cast<float4*>(srow + 8 + p0 + 4) = make_float4(w[12], w[13], w[14], w[15]);
    if (lane == 0) {
        float4 pad = make_float4(1e12f, 1e12f, 1e12f, 1e12f);
        *reinterpret_cast<float4*>(srow)     = pad;
        *reinterpret_cast<float4*>(srow + 4) = pad;
    }
    if (lane == 63) {
        float4 pad = make_float4(1e12f, 1e12f, 1e12f, 1e12f);
        *reinterpret_cast<float4*>(srow + 520) = pad;
        *reinterpret_cast<float4*>(srow + 524) = pad;
    }
    // row buffer is private to this wave: lockstep ds_write -> ds_read, no barrier

    float4 l0 = *reinterpret_cast<float4*>(srow + p0);
    float4 l1 = *reinterpret_cast<float4*>(srow + p0 + 4);
    float4 r0 = *reinterpret_cast<float4*>(srow + p0 + 16);
    float4 r1 = *reinterpret_cast<float4*>(srow + p0 + 20);
    w[0]  = l0.x; w[1]  = l0.y; w[2]  = l0.z; w[3]  = l0.w;
    w[4]  = l1.x; w[5]  = l1.y; w[6]  = l1.z; w[7]  = l1.w;
    w[16] = r0.x; w[17] = r0.y; w[18] = r0.z; w[19] = r0.w;
    w[20] = r1.x; w[21] = r1.y; w[22] = r1.z; w[23] = r1.w;

    bool mk[8];
    mk[0] = (b0.x >> bit) & 1u; mk[1] = (b0.y >> bit) & 1u;
    mk[2] = (b0.z >> bit) & 1u; mk[3] = (b0.w >> bit) & 1u;
    mk[4] = (b1.x >> bit) & 1u; mk[5] = (b1.y >> bit) & 1u;
    mk[6] = (b1.z >> bit) & 1u; mk[7] = (b1.w >> bit) & 1u;
    int anyb = 0;
    #pragma unroll
    for (int p = 0; p < 8; ++p) anyb |= (int)mk[p];

    // exact envelope, r<=8 fully in registers
    float best[8];
    #pragma unroll
    for (int p = 0; p < 8; ++p) best[p] = w[8 + p];
    #pragma unroll
    for (int r = 1; r <= 8; ++r) {
        const float rr = (float)(r * r);
        #pragma unroll
        for (int p = 0; p < 8; ++p)
            best[p] = fminf(best[p], fminf(rr + w[8 + p - r], rr + w[8 + p + r]));
    }

    // remaining candidates cost >= 81; rare exact fallback via LDS
    float bmax = 0.0f;
    #pragma unroll
    for (int p = 0; p < 8; ++p) bmax = fmaxf(bmax, mk[p] ? best[p] : 0.0f);
    if (!__all(bmax <= 81.0f)) {
        for (int r = 9; r < W; ++r) {
            const float rr = (float)(r * r);
            if (__all(rr >= bmax)) break;
            #pragma unroll
            for (int p = 0; p < 8; ++p) {
                int kl = p0 + p - r, kr = p0 + p + r;
                float cl = (kl >= 0) ? srow[8 + kl] : 1.0e12f;
                float cr = (kr < W)  ? srow[8 + kr] : 1.0e12f;
                best[p] = fminf(best[p], fminf(rr + cl, rr + cr));
            }
            bmax = 0.0f;
            #pragma unroll
            for (int p = 0; p < 8; ++p) bmax = fmaxf(bmax, mk[p] ? best[p] : 0.0f);
        }
    }

    // masked max: lane -> wave -> block -> atomic; last block finalizes
    float v = 0.0f;
    #pragma unroll
    for (int p = 0; p < 8; ++p) v = fmaxf(v, mk[p] ? best[p] : 0.0f);
    #pragma unroll
    for (int off = 32; off > 0; off >>= 1)
        v = fmaxf(v, __shfl_down(v, off, 64));
    int wany = __any(anyb) ? 1 : 0;
    if (lane == 0) { s_wmax[wave] = v; s_wany[wave] = wany; }
    __syncthreads();
    if (threadIdx.x == 0) {
        float mx = s_wmax[0]; int af = s_wany[0];
        #pragma unroll
        for (int q = 1; q < 8; ++q) { mx = fmaxf(mx, s_wmax[q]); af |= s_wany[q]; }
        atomicMax((int*)&maxsq[task], __float_as_int(mx));   // values >= 0: int order == float order
        if (af) atomicOr(&anyflag[msel], 1);
        __threadfence();
        int prev = atomicAdd(done, 1);
        if (prev == (int)(gridDim.x * gridDim.y) - 1) {
            // all blocks' atomics are visible; read back via idempotent atomics
            float s = 0.0f;
            for (int i2 = 0; i2 < NIMG; ++i2) {
                int af1 = atomicOr(&anyflag[i2], 0);
                int af2 = atomicOr(&anyflag[NIMG + i2], 0);
                float m1 = __int_as_float(atomicMax((int*)&maxsq[i2], 0));
                float m2 = __int_as_float(atomicMax((int*)&maxsq[NIMG + i2], 0));
                float loss;
                if (!af1 || !af2) {
                    loss = 1.0f;
                } else {
                    float hd = sqrtf(fmaxf(m1, m2));
                    loss = 1.0f - 1.0f / (1.0f + hd);
                }
                s += loss;
            }
            out[0] = s * (1.0f / (float)NIMG);
        }
    }
}

extern "C" void kernel_launch(void* const* d_in, const int* in_sizes, int n_in,
                              void* d_out, int out_size, void* d_ws, size_t ws_size,
                              hipStream_t stream) {
    const float* A = (const float*)d_in[0];
    const float* B = (const float*)d_in[1];
    char* base = (char*)d_ws;
    unsigned short* F = (unsigned short*)base;
    float* maxsq      = (float*)(base + (size_t)16 * H * W * sizeof(unsigned short));
    int*   anyflag    = (int*)((char*)maxsq + 64);
    int*   done       = (int*)((char*)maxsq + 128);
    unsigned int* bm  = (unsigned int*)((char*)maxsq + 256);
    float* out        = (float*)d_out;

    hipLaunchKernelGGL(k_col_edt, dim3(W / 32, 16), dim3(128), 0, stream,
                       A, B, F, bm, maxsq, anyflag, done);
    hipLaunchKernelGGL(k_row_env, dim3(H / 8, 16), dim3(512), 0, stream,
                       F, bm, maxsq, anyflag, done, out);
}

// Round 6
// 32.960 us; speedup vs baseline: 1.4257x; 1.4257x over previous
//
#include <hip/hip_runtime.h>
#include <hip/hip_bf16.h>

static constexpr int H = 512;
static constexpr int W = 512;
static constexpr int NIMG = 8;

// ws layout (bytes from d_ws):
//   F       @ 0        : [16][H][W] u16 = 8 MiB (axis-0 distance; 0xFFFF = empty column)
//   maxsq   @ 8Mi      : 16 f32  (task = dir*8+img; dir0 = max_{a} D_b^2, dir1 = max_{b} D_a^2)
//   anyflag @ 8Mi+64   : 16 int  (t<8: any(a_t), t>=8: any(b_{t-8}))
//   bm      @ 8Mi+256  : [16][16][512] u32 = 512 KiB (bit r of bm[m][s][c] = mask m pixel (s*32+r, c))

__device__ __forceinline__ int edt_d(unsigned int m, int r, int row0, int ig,
                                     int carry_dn, int carry_up) {
    unsigned int below = m & (0xFFFFFFFFu >> (31 - r));   // bits 0..r
    int pos_dn = below ? (row0 + (31 - __clz((int)below))) : carry_dn;
    unsigned int above = m & (0xFFFFFFFFu << r);          // bits r..31
    int pos_up = above ? (row0 + (__ffs((int)above) - 1)) : carry_up;
    return min(ig - pos_dn, pos_up - ig);
}

__global__ __launch_bounds__(128)
void k_col_edt(const float* __restrict__ A, const float* __restrict__ B,
               unsigned short* __restrict__ F, unsigned int* __restrict__ bm,
               float* __restrict__ maxsq, int* __restrict__ anyflag) {
    const int tid  = threadIdx.x;
    const int quad = tid & 7;          // 4-column group within 32-col tile
    const int seg  = tid >> 3;         // 0..15 (32-row segment)
    const int cg   = blockIdx.x;       // 0..15
    const int m16  = blockIdx.y;       // 0..15

    // fold k_init: only this block writes the slots; k_row_env (stream-ordered
    // after) is the only accumulator. ws is poisoned once, so re-init each call.
    if (cg == 0 && m16 == 0 && tid < 16) { maxsq[tid] = 0.0f; anyflag[tid] = 0; }

    const int colbase = cg * 32 + quad * 4;
    const float* src = (m16 < NIMG) ? (A + (size_t)m16 * H * W)
                                    : (B + (size_t)(m16 - NIMG) * H * W);
    unsigned short* f = F + (size_t)m16 * H * W;
    const int row0 = seg * 32;

    // 32 independent float4 loads -> 4 column bitmasks
    unsigned int m0 = 0, m1 = 0, m2 = 0, m3 = 0;
    #pragma unroll
    for (int r = 0; r < 32; ++r) {
        float4 v = *reinterpret_cast<const float4*>(src + (size_t)(row0 + r) * W + colbase);
        m0 |= (v.x > 0.5f ? 1u : 0u) << r;
        m1 |= (v.y > 0.5f ? 1u : 0u) << r;
        m2 |= (v.z > 0.5f ? 1u : 0u) << r;
        m3 |= (v.w > 0.5f ? 1u : 0u) << r;
    }

    // persist bitmasks for k_row_env's membership test (replaces float mask re-read)
    {
        uint4 o = make_uint4(m0, m1, m2, m3);
        *reinterpret_cast<uint4*>(&bm[((size_t)m16 * 16 + seg) * W + colbase]) = o;
    }

    const int NEGS = -(1 << 21), POSS = (1 << 21);
    __shared__ int s_hi[16][32];
    __shared__ int s_lo[16][32];
    int4 hi, lo;
    hi.x = m0 ? (row0 + 31 - __clz((int)m0)) : NEGS;
    hi.y = m1 ? (row0 + 31 - __clz((int)m1)) : NEGS;
    hi.z = m2 ? (row0 + 31 - __clz((int)m2)) : NEGS;
    hi.w = m3 ? (row0 + 31 - __clz((int)m3)) : NEGS;
    lo.x = m0 ? (row0 + __ffs((int)m0) - 1) : POSS;
    lo.y = m1 ? (row0 + __ffs((int)m1) - 1) : POSS;
    lo.z = m2 ? (row0 + __ffs((int)m2) - 1) : POSS;
    lo.w = m3 ? (row0 + __ffs((int)m3) - 1) : POSS;
    *reinterpret_cast<int4*>(&s_hi[seg][quad * 4]) = hi;
    *reinterpret_cast<int4*>(&s_lo[seg][quad * 4]) = lo;
    __syncthreads();

    // cross-segment carries (vectorized over the 4 owned columns)
    int4 cdn = {NEGS, NEGS, NEGS, NEGS};
    for (int t = 0; t < seg; ++t) {
        int4 h = *reinterpret_cast<int4*>(&s_hi[t][quad * 4]);
        cdn.x = max(cdn.x, h.x); cdn.y = max(cdn.y, h.y);
        cdn.z = max(cdn.z, h.z); cdn.w = max(cdn.w, h.w);
    }
    int4 cup = {POSS, POSS, POSS, POSS};
    for (int t = seg + 1; t < 16; ++t) {
        int4 l = *reinterpret_cast<int4*>(&s_lo[t][quad * 4]);
        cup.x = min(cup.x, l.x); cup.y = min(cup.y, l.y);
        cup.z = min(cup.z, l.z); cup.w = min(cup.w, l.w);
    }

    // per-row exact axis-0 distance, packed ushort4 stores
    #pragma unroll
    for (int r = 0; r < 32; ++r) {
        const int ig = row0 + r;
        ushort4 o;
        o.x = (unsigned short)min(edt_d(m0, r, row0, ig, cdn.x, cup.x), 65535);
        o.y = (unsigned short)min(edt_d(m1, r, row0, ig, cdn.y, cup.y), 65535);
        o.z = (unsigned short)min(edt_d(m2, r, row0, ig, cdn.z, cup.z), 65535);
        o.w = (unsigned short)min(edt_d(m3, r, row0, ig, cdn.w, cup.w), 65535);
        *reinterpret_cast<ushort4*>(f + (size_t)ig * W + colbase) = o;
    }
}

__global__ __launch_bounds__(512)
void k_row_env(const unsigned short* __restrict__ F, const unsigned int* __restrict__ bm,
               float* __restrict__ maxsq, int* __restrict__ anyflag) {
    const int task = blockIdx.y;            // 0..15
    const int img  = task & 7;
    const int dir  = task >> 3;             // 0: D_b at a-pixels ; 1: D_a at b-pixels
    const int wave = threadIdx.x >> 6;      // 0..7 -> row within block
    const int lane = threadIdx.x & 63;
    const int row  = blockIdx.x * 8 + wave;
    const int fsel = (dir == 0) ? (NIMG + img) : img;   // EDT source (the other mask)
    const int msel = (dir == 0) ? img : (NIMG + img);   // membership mask
    const unsigned short* frow = F + (size_t)fsel * H * W + (size_t)row * W;
    const int p0 = lane * 8;

    __shared__ float sf[8][512];            // fallback-only row buffer (wave-private)
    __shared__ float s_wmax[8];
    __shared__ int   s_wany[8];

    // independent 16B loads: f (8x u16) + membership bits (8x u32, L2-resident bm)
    uint4 fu = *reinterpret_cast<const uint4*>(frow + p0);
    const unsigned int* brow = bm + ((size_t)msel * 16 + (row >> 5)) * W + p0;
    uint4 b0 = *reinterpret_cast<const uint4*>(brow);
    uint4 b1 = *reinterpret_cast<const uint4*>(brow + 4);
    const int bit = row & 31;

    // w[8..15] = own f values; w[0..7] / w[16..23] = +-8 halo via lane shuffles
    float w[24];
    {
        unsigned int uu[4] = {fu.x, fu.y, fu.z, fu.w};
        #pragma unroll
        for (int e = 0; e < 4; ++e) {
            int dl = (int)(uu[e] & 0xFFFFu);
            int dh = (int)(uu[e] >> 16);
            w[8 + 2 * e]     = (dl == 65535) ? 1.0e12f : (float)(dl * dl);
            w[8 + 2 * e + 1] = (dh == 65535) ? 1.0e12f : (float)(dh * dh);
        }
    }
    #pragma unroll
    for (int e = 0; e < 8; ++e) {
        w[e]      = __shfl_up(w[8 + e], 1, 64);     // lane-1's elements = p0-8+e
        w[16 + e] = __shfl_down(w[8 + e], 1, 64);   // lane+1's elements = p0+8+e
    }
    if (lane == 0) {
        #pragma unroll
        for (int e = 0; e < 8; ++e) w[e] = 1.0e12f;
    }
    if (lane == 63) {
        #pragma unroll
        for (int e = 0; e < 8; ++e) w[16 + e] = 1.0e12f;
    }

    bool mk[8];
    mk[0] = (b0.x >> bit) & 1u; mk[1] = (b0.y >> bit) & 1u;
    mk[2] = (b0.z >> bit) & 1u; mk[3] = (b0.w >> bit) & 1u;
    mk[4] = (b1.x >> bit) & 1u; mk[5] = (b1.y >> bit) & 1u;
    mk[6] = (b1.z >> bit) & 1u; mk[7] = (b1.w >> bit) & 1u;
    int anyb = 0;
    #pragma unroll
    for (int p = 0; p < 8; ++p) anyb |= (int)mk[p];

    // exact envelope, r<=8 fully in registers
    float best[8];
    #pragma unroll
    for (int p = 0; p < 8; ++p) best[p] = w[8 + p];
    #pragma unroll
    for (int r = 1; r <= 8; ++r) {
        const float rr = (float)(r * r);
        #pragma unroll
        for (int p = 0; p < 8; ++p)
            best[p] = fminf(best[p], fminf(rr + w[8 + p - r], rr + w[8 + p + r]));
    }

    // remaining candidates cost >= 81; rare exact fallback (wave-uniform entry,
    // wave-private LDS row filled lockstep here -> no barrier needed)
    float bmax = 0.0f;
    #pragma unroll
    for (int p = 0; p < 8; ++p) bmax = fmaxf(bmax, mk[p] ? best[p] : 0.0f);
    if (!__all(bmax <= 81.0f)) {
        float* srow = &sf[wave][0];
        *reinterpret_cast<float4*>(srow + p0)     = make_float4(w[8],  w[9],  w[10], w[11]);
        *reinterpret_cast<float4*>(srow + p0 + 4) = make_float4(w[12], w[13], w[14], w[15]);
        for (int r = 9; r < W; ++r) {
            const float rr = (float)(r * r);
            if (__all(rr >= bmax)) break;
            #pragma unroll
            for (int p = 0; p < 8; ++p) {
                int kl = p0 + p - r, kr = p0 + p + r;
                float cl = (kl >= 0) ? srow[kl] : 1.0e12f;
                float cr = (kr < W)  ? srow[kr] : 1.0e12f;
                best[p] = fminf(best[p], fminf(rr + cl, rr + cr));
            }
            bmax = 0.0f;
            #pragma unroll
            for (int p = 0; p < 8; ++p) bmax = fmaxf(bmax, mk[p] ? best[p] : 0.0f);
        }
    }

    // masked max: lane -> wave -> block -> one atomic per block
    float v = 0.0f;
    #pragma unroll
    for (int p = 0; p < 8; ++p) v = fmaxf(v, mk[p] ? best[p] : 0.0f);
    #pragma unroll
    for (int off = 32; off > 0; off >>= 1)
        v = fmaxf(v, __shfl_down(v, off, 64));
    int wany = __any(anyb) ? 1 : 0;
    if (lane == 0) { s_wmax[wave] = v; s_wany[wave] = wany; }
    __syncthreads();
    if (threadIdx.x == 0) {
        float mx = s_wmax[0]; int af = s_wany[0];
        #pragma unroll
        for (int q = 1; q < 8; ++q) { mx = fmaxf(mx, s_wmax[q]); af |= s_wany[q]; }
        atomicMax((int*)&maxsq[task], __float_as_int(mx));   // values >= 0: int order == float order
        if (af) atomicOr(&anyflag[msel], 1);
    }
}

__global__ void k_finalize(const float* __restrict__ maxsq, const int* __restrict__ anyflag,
                           float* __restrict__ out) {
    if (threadIdx.x == 0 && blockIdx.x == 0) {
        float s = 0.0f;
        for (int img = 0; img < NIMG; ++img) {
            bool empty = (anyflag[img] == 0) || (anyflag[NIMG + img] == 0);
            float loss;
            if (empty) {
                loss = 1.0f;
            } else {
                float hd = sqrtf(fmaxf(maxsq[img], maxsq[NIMG + img]));
                loss = 1.0f - 1.0f / (1.0f + hd);
            }
            s += loss;
        }
        out[0] = s * (1.0f / (float)NIMG);
    }
}

extern "C" void kernel_launch(void* const* d_in, const int* in_sizes, int n_in,
                              void* d_out, int out_size, void* d_ws, size_t ws_size,
                              hipStream_t stream) {
    const float* A = (const float*)d_in[0];
    const float* B = (const float*)d_in[1];
    char* base = (char*)d_ws;
    unsigned short* F = (unsigned short*)base;
    float* maxsq      = (float*)(base + (size_t)16 * H * W * sizeof(unsigned short));
    int*   anyflag    = (int*)((char*)maxsq + 64);
    unsigned int* bm  = (unsigned int*)((char*)maxsq + 256);
    float* out        = (float*)d_out;

    hipLaunchKernelGGL(k_col_edt, dim3(W / 32, 16), dim3(128), 0, stream,
                       A, B, F, bm, maxsq, anyflag);
    hipLaunchKernelGGL(k_row_env, dim3(H / 8, 16), dim3(512), 0, stream,
                       F, bm, maxsq, anyflag);
    hipLaunchKernelGGL(k_finalize, dim3(1), dim3(1), 0, stream, maxsq, anyflag, out);
}

// Round 7
// 31.083 us; speedup vs baseline: 1.5118x; 1.0604x over previous
//
#include <hip/hip_runtime.h>
#include <hip/hip_bf16.h>

static constexpr int H = 512;
static constexpr int W = 512;
static constexpr int NIMG = 8;

// ws layout (bytes from d_ws):
//   F       @ 0        : [16][H][W] u16 = 8 MiB (axis-0 distance; 0xFFFF = empty column)
//   maxsq   @ 8Mi      : 16 f32  (task = dir*8+img; dir0 = max_{a} D_b^2, dir1 = max_{b} D_a^2)
//   anyflag @ 8Mi+64   : 16 int  (t<8: any(a_t), t>=8: any(b_{t-8}))
//   bm      @ 8Mi+256  : [16][16][512] u32 = 512 KiB (bit r of bm[m][s][c] = mask m pixel (s*32+r, c))

__device__ __forceinline__ int edt_d(unsigned int m, int r, int row0, int ig,
                                     int carry_dn, int carry_up) {
    unsigned int below = m & (0xFFFFFFFFu >> (31 - r));   // bits 0..r
    int pos_dn = below ? (row0 + (31 - __clz((int)below))) : carry_dn;
    unsigned int above = m & (0xFFFFFFFFu << r);          // bits r..31
    int pos_up = above ? (row0 + (__ffs((int)above) - 1)) : carry_up;
    return min(ig - pos_dn, pos_up - ig);
}

// 512 threads: quad = tid&7 (4-col group, 32 cols/block), seg = tid>>3 (0..63, 8 rows each).
// 4 consecutive segs form a 32-row window; masks or-combined across sub-lanes via shfl_xor.
__global__ __launch_bounds__(512)
void k_col_edt(const float* __restrict__ A, const float* __restrict__ B,
               unsigned short* __restrict__ F, unsigned int* __restrict__ bm,
               float* __restrict__ maxsq, int* __restrict__ anyflag) {
    const int tid  = threadIdx.x;
    const int quad = tid & 7;
    const int seg  = tid >> 3;          // 0..63
    const int sub  = seg & 3;           // byte position within 32-row window
    const int win  = seg >> 2;          // 0..15 (32-row window)
    const int cg   = blockIdx.x;        // 0..15
    const int m16  = blockIdx.y;        // 0..15

    // fold k_init: only this block writes the slots; k_row_env (stream-ordered
    // after) is the only accumulator. ws is poisoned once, so re-init each call.
    if (cg == 0 && m16 == 0 && tid < 16) { maxsq[tid] = 0.0f; anyflag[tid] = 0; }

    const int colbase = cg * 32 + quad * 4;
    const float* src = (m16 < NIMG) ? (A + (size_t)m16 * H * W)
                                    : (B + (size_t)(m16 - NIMG) * H * W);
    unsigned short* f = F + (size_t)m16 * H * W;
    const int row0 = seg * 8;           // this thread's 8 rows
    const int w0   = win * 32;          // window start row

    // 8 independent float4 loads -> 4 column 8-bit masks
    unsigned int m0 = 0, m1 = 0, m2 = 0, m3 = 0;
    #pragma unroll
    for (int r = 0; r < 8; ++r) {
        float4 v = *reinterpret_cast<const float4*>(src + (size_t)(row0 + r) * W + colbase);
        m0 |= (v.x > 0.5f ? 1u : 0u) << r;
        m1 |= (v.y > 0.5f ? 1u : 0u) << r;
        m2 |= (v.z > 0.5f ? 1u : 0u) << r;
        m3 |= (v.w > 0.5f ? 1u : 0u) << r;
    }

    // assemble full 32-bit window masks: place own byte, or-combine across the
    // window's 4 sub-lanes (lane^8 -> seg^1, lane^16 -> seg^2; wave-internal)
    const int sh = 8 * sub;
    m0 <<= sh; m1 <<= sh; m2 <<= sh; m3 <<= sh;
    m0 |= __shfl_xor(m0, 8, 64);  m0 |= __shfl_xor(m0, 16, 64);
    m1 |= __shfl_xor(m1, 8, 64);  m1 |= __shfl_xor(m1, 16, 64);
    m2 |= __shfl_xor(m2, 8, 64);  m2 |= __shfl_xor(m2, 16, 64);
    m3 |= __shfl_xor(m3, 8, 64);  m3 |= __shfl_xor(m3, 16, 64);

    const int NEGS = -(1 << 21), POSS = (1 << 21);
    __shared__ int s_hi[16][32];
    __shared__ int s_lo[16][32];
    if (sub == 0) {
        int4 hi, lo;
        hi.x = m0 ? (w0 + 31 - __clz((int)m0)) : NEGS;
        hi.y = m1 ? (w0 + 31 - __clz((int)m1)) : NEGS;
        hi.z = m2 ? (w0 + 31 - __clz((int)m2)) : NEGS;
        hi.w = m3 ? (w0 + 31 - __clz((int)m3)) : NEGS;
        lo.x = m0 ? (w0 + __ffs((int)m0) - 1) : POSS;
        lo.y = m1 ? (w0 + __ffs((int)m1) - 1) : POSS;
        lo.z = m2 ? (w0 + __ffs((int)m2) - 1) : POSS;
        lo.w = m3 ? (w0 + __ffs((int)m3) - 1) : POSS;
        *reinterpret_cast<int4*>(&s_hi[win][quad * 4]) = hi;
        *reinterpret_cast<int4*>(&s_lo[win][quad * 4]) = lo;
        // persist bitmasks for k_row_env's membership test
        uint4 o = make_uint4(m0, m1, m2, m3);
        *reinterpret_cast<uint4*>(&bm[((size_t)m16 * 16 + win) * W + colbase]) = o;
    }
    __syncthreads();

    // cross-window carries (vectorized over the 4 owned columns)
    int4 cdn = {NEGS, NEGS, NEGS, NEGS};
    for (int t = 0; t < win; ++t) {
        int4 h = *reinterpret_cast<int4*>(&s_hi[t][quad * 4]);
        cdn.x = max(cdn.x, h.x); cdn.y = max(cdn.y, h.y);
        cdn.z = max(cdn.z, h.z); cdn.w = max(cdn.w, h.w);
    }
    int4 cup = {POSS, POSS, POSS, POSS};
    for (int t = win + 1; t < 16; ++t) {
        int4 l = *reinterpret_cast<int4*>(&s_lo[t][quad * 4]);
        cup.x = min(cup.x, l.x); cup.y = min(cup.y, l.y);
        cup.z = min(cup.z, l.z); cup.w = min(cup.w, l.w);
    }

    // per-row exact axis-0 distance for this thread's 8 rows, packed ushort4 stores
    #pragma unroll
    for (int k = 0; k < 8; ++k) {
        const int ig = row0 + k;        // global row
        const int rb = sub * 8 + k;     // bit index within window
        ushort4 o;
        o.x = (unsigned short)min(edt_d(m0, rb, w0, ig, cdn.x, cup.x), 65535);
        o.y = (unsigned short)min(edt_d(m1, rb, w0, ig, cdn.y, cup.y), 65535);
        o.z = (unsigned short)min(edt_d(m2, rb, w0, ig, cdn.z, cup.z), 65535);
        o.w = (unsigned short)min(edt_d(m3, rb, w0, ig, cdn.w, cup.w), 65535);
        *reinterpret_cast<ushort4*>(f + (size_t)ig * W + colbase) = o;
    }
}

__global__ __launch_bounds__(512)
void k_row_env(const unsigned short* __restrict__ F, const unsigned int* __restrict__ bm,
               float* __restrict__ maxsq, int* __restrict__ anyflag) {
    const int task = blockIdx.y;            // 0..15
    const int img  = task & 7;
    const int dir  = task >> 3;             // 0: D_b at a-pixels ; 1: D_a at b-pixels
    const int wave = threadIdx.x >> 6;      // 0..7 -> row within block
    const int lane = threadIdx.x & 63;
    const int row  = blockIdx.x * 8 + wave;
    const int fsel = (dir == 0) ? (NIMG + img) : img;   // EDT source (the other mask)
    const int msel = (dir == 0) ? img : (NIMG + img);   // membership mask
    const unsigned short* frow = F + (size_t)fsel * H * W + (size_t)row * W;
    const int p0 = lane * 8;

    __shared__ float sf[8][512];            // fallback-only row buffer (wave-private)
    __shared__ float s_wmax[8];
    __shared__ int   s_wany[8];

    // independent 16B loads: f (8x u16) + membership bits (8x u32, L2-resident bm)
    uint4 fu = *reinterpret_cast<const uint4*>(frow + p0);
    const unsigned int* brow = bm + ((size_t)msel * 16 + (row >> 5)) * W + p0;
    uint4 b0 = *reinterpret_cast<const uint4*>(brow);
    uint4 b1 = *reinterpret_cast<const uint4*>(brow + 4);
    const int bit = row & 31;

    // w[8..15] = own f values; w[0..7] / w[16..23] = +-8 halo via lane shuffles
    float w[24];
    {
        unsigned int uu[4] = {fu.x, fu.y, fu.z, fu.w};
        #pragma unroll
        for (int e = 0; e < 4; ++e) {
            int dl = (int)(uu[e] & 0xFFFFu);
            int dh = (int)(uu[e] >> 16);
            w[8 + 2 * e]     = (dl == 65535) ? 1.0e12f : (float)(dl * dl);
            w[8 + 2 * e + 1] = (dh == 65535) ? 1.0e12f : (float)(dh * dh);
        }
    }
    #pragma unroll
    for (int e = 0; e < 8; ++e) {
        w[e]      = __shfl_up(w[8 + e], 1, 64);     // lane-1's elements = p0-8+e
        w[16 + e] = __shfl_down(w[8 + e], 1, 64);   // lane+1's elements = p0+8+e
    }
    if (lane == 0) {
        #pragma unroll
        for (int e = 0; e < 8; ++e) w[e] = 1.0e12f;
    }
    if (lane == 63) {
        #pragma unroll
        for (int e = 0; e < 8; ++e) w[16 + e] = 1.0e12f;
    }

    bool mk[8];
    mk[0] = (b0.x >> bit) & 1u; mk[1] = (b0.y >> bit) & 1u;
    mk[2] = (b0.z >> bit) & 1u; mk[3] = (b0.w >> bit) & 1u;
    mk[4] = (b1.x >> bit) & 1u; mk[5] = (b1.y >> bit) & 1u;
    mk[6] = (b1.z >> bit) & 1u; mk[7] = (b1.w >> bit) & 1u;
    int anyb = 0;
    #pragma unroll
    for (int p = 0; p < 8; ++p) anyb |= (int)mk[p];

    // exact envelope, r<=8 fully in registers
    float best[8];
    #pragma unroll
    for (int p = 0; p < 8; ++p) best[p] = w[8 + p];
    #pragma unroll
    for (int r = 1; r <= 8; ++r) {
        const float rr = (float)(r * r);
        #pragma unroll
        for (int p = 0; p < 8; ++p)
            best[p] = fminf(best[p], fminf(rr + w[8 + p - r], rr + w[8 + p + r]));
    }

    // remaining candidates cost >= 81; rare exact fallback (wave-uniform entry,
    // wave-private LDS row filled lockstep here -> no barrier needed)
    float bmax = 0.0f;
    #pragma unroll
    for (int p = 0; p < 8; ++p) bmax = fmaxf(bmax, mk[p] ? best[p] : 0.0f);
    if (!__all(bmax <= 81.0f)) {
        float* srow = &sf[wave][0];
        *reinterpret_cast<float4*>(srow + p0)     = make_float4(w[8],  w[9],  w[10], w[11]);
        *reinterpret_cast<float4*>(srow + p0 + 4) = make_float4(w[12], w[13], w[14], w[15]);
        for (int r = 9; r < W; ++r) {
            const float rr = (float)(r * r);
            if (__all(rr >= bmax)) break;
            #pragma unroll
            for (int p = 0; p < 8; ++p) {
                int kl = p0 + p - r, kr = p0 + p + r;
                float cl = (kl >= 0) ? srow[kl] : 1.0e12f;
                float cr = (kr < W)  ? srow[kr] : 1.0e12f;
                best[p] = fminf(best[p], fminf(rr + cl, rr + cr));
            }
            bmax = 0.0f;
            #pragma unroll
            for (int p = 0; p < 8; ++p) bmax = fmaxf(bmax, mk[p] ? best[p] : 0.0f);
        }
    }

    // masked max: lane -> wave -> block -> one atomic per block
    float v = 0.0f;
    #pragma unroll
    for (int p = 0; p < 8; ++p) v = fmaxf(v, mk[p] ? best[p] : 0.0f);
    #pragma unroll
    for (int off = 32; off > 0; off >>= 1)
        v = fmaxf(v, __shfl_down(v, off, 64));
    int wany = __any(anyb) ? 1 : 0;
    if (lane == 0) { s_wmax[wave] = v; s_wany[wave] = wany; }
    __syncthreads();
    if (threadIdx.x == 0) {
        float mx = s_wmax[0]; int af = s_wany[0];
        #pragma unroll
        for (int q = 1; q < 8; ++q) { mx = fmaxf(mx, s_wmax[q]); af |= s_wany[q]; }
        atomicMax((int*)&maxsq[task], __float_as_int(mx));   // values >= 0: int order == float order
        if (af) atomicOr(&anyflag[msel], 1);
    }
}

__global__ void k_finalize(const float* __restrict__ maxsq, const int* __restrict__ anyflag,
                           float* __restrict__ out) {
    if (threadIdx.x == 0 && blockIdx.x == 0) {
        float s = 0.0f;
        for (int img = 0; img < NIMG; ++img) {
            bool empty = (anyflag[img] == 0) || (anyflag[NIMG + img] == 0);
            float loss;
            if (empty) {
                loss = 1.0f;
            } else {
                float hd = sqrtf(fmaxf(maxsq[img], maxsq[NIMG + img]));
                loss = 1.0f - 1.0f / (1.0f + hd);
            }
            s += loss;
        }
        out[0] = s * (1.0f / (float)NIMG);
    }
}

extern "C" void kernel_launch(void* const* d_in, const int* in_sizes, int n_in,
                              void* d_out, int out_size, void* d_ws, size_t ws_size,
                              hipStream_t stream) {
    const float* A = (const float*)d_in[0];
    const float* B = (const float*)d_in[1];
    char* base = (char*)d_ws;
    unsigned short* F = (unsigned short*)base;
    float* maxsq      = (float*)(base + (size_t)16 * H * W * sizeof(unsigned short));
    int*   anyflag    = (int*)((char*)maxsq + 64);
    unsigned int* bm  = (unsigned int*)((char*)maxsq + 256);
    float* out        = (float*)d_out;

    hipLaunchKernelGGL(k_col_edt, dim3(W / 32, 16), dim3(512), 0, stream,
                       A, B, F, bm, maxsq, anyflag);
    hipLaunchKernelGGL(k_row_env, dim3(H / 8, 16), dim3(512), 0, stream,
                       F, bm, maxsq, anyflag);
    hipLaunchKernelGGL(k_finalize, dim3(1), dim3(1), 0, stream, maxsq, anyflag, out);
}